// Round 1
// baseline (43.783 us; speedup 1.0000x reference)
//
#include <hip/hip_runtime.h>
#include <math.h>

// Problem constants (from reference setup_inputs)
#define BB 16
#define QQ 900
#define NC 92
#define TT 1600
#define BQ (BB * QQ)   // 14400

// ---- workspace layout (all small, < 160 KB) ----
// [0]       float2 rowstats[BQ]   : (max_logit, 1/sum_exp)   = 115200 B
// [115200]  float4 tgt_xyxy[TT]                               =  25600 B
// [140800]  float  tgt_area[TT]                               =   6400 B
// [147200]  int    tgt_id[TT]                                 =   6400 B
#define WS_STATS  0
#define WS_XYXY   115200
#define WS_AREA   140800
#define WS_ID     147200

// ---------------------------------------------------------------------------
// Kernel A: per-row softmax stats. One wave (64 lanes) per row of NC=92.
// ---------------------------------------------------------------------------
__global__ __launch_bounds__(256)
void k_rowstats(const float* __restrict__ logits, float2* __restrict__ stats) {
    const int wave = threadIdx.x >> 6;         // 0..3
    const int lane = threadIdx.x & 63;
    const int row  = blockIdx.x * 4 + wave;    // grid.x = BQ/4 = 3600 exact
    const float* lr = logits + (long)row * NC;
    float v0 = lr[lane];                              // lanes 0..63 valid (NC=92)
    float v1 = (lane < NC - 64) ? lr[64 + lane] : -INFINITY;
    float m = fmaxf(v0, v1);
    #pragma unroll
    for (int off = 32; off; off >>= 1) m = fmaxf(m, __shfl_xor(m, off));
    float s = __expf(v0 - m) + ((lane < NC - 64) ? __expf(v1 - m) : 0.0f);
    #pragma unroll
    for (int off = 32; off; off >>= 1) s += __shfl_xor(s, off);
    if (lane == 0) stats[row] = make_float2(m, 1.0f / s);
}

// ---------------------------------------------------------------------------
// Kernel B: target preprocessing (cxcywh -> xyxy, area, id copy).
// ---------------------------------------------------------------------------
__global__ __launch_bounds__(256)
void k_tgt(const float* __restrict__ tbox, const int* __restrict__ tids,
           float4* __restrict__ t_xyxy, float* __restrict__ t_area,
           int* __restrict__ t_id) {
    const int t = blockIdx.x * blockDim.x + threadIdx.x;
    if (t >= TT) return;
    float4 b = ((const float4*)tbox)[t];            // cx, cy, w, h
    float x0 = b.x - 0.5f * b.z, y0 = b.y - 0.5f * b.w;
    float x1 = b.x + 0.5f * b.z, y1 = b.y + 0.5f * b.w;
    t_xyxy[t] = make_float4(x0, y0, x1, y1);
    t_area[t] = (x1 - x0) * (y1 - y0);
    t_id[t]   = tids[t];
}

// ---------------------------------------------------------------------------
// Kernel C: main cost kernel.
//   block = 256 threads = 64 t-lanes x 4 row-groups; each thread owns 4 rows
//   (register-blocked box data) -> 16 rows per block.
//   grid = (BQ/16 = 900, TT/320 = 5); each block: 16 rows x 320 targets.
//   LDS: negated softmax probs for the 16 rows (16 x 92 fp32 = 5.9 KB).
//   Target data read straight from global (64 KB total -> L2-resident).
// ---------------------------------------------------------------------------
#define RT 4        // rows per thread
#define RTILE 16    // rows per block
#define TK 5        // t-iterations of 64 -> 320 targets per block

__global__ __launch_bounds__(256)
void k_cost(const float* __restrict__ logits,
            const float* __restrict__ boxes,       // [BQ,4] cxcywh
            const float2* __restrict__ stats,
            const float4* __restrict__ t_xyxy,
            const float* __restrict__ t_area,
            const int* __restrict__ t_id,
            const float* __restrict__ tbox_raw,    // [TT,4] cxcywh
            float* __restrict__ out) {
    __shared__ float negp[RTILE][NC];              // 5888 B

    const int row0 = blockIdx.x * RTILE;
    const int t0   = blockIdx.y * (TK * 64);

    // stage -prob for the 16 rows of this block
    for (int idx = threadIdx.x; idx < RTILE * NC; idx += 256) {
        int r = idx / NC, c = idx - r * NC;
        int row = row0 + r;
        float2 st = stats[row];
        negp[r][c] = -__expf(logits[(long)row * NC + c] - st.x) * st.y;
    }

    const int tl = threadIdx.x & 63;
    const int rg = threadIdx.x >> 6;
    const int rbase = row0 + rg * RT;

    // register-blocked row box data (loads are wave-broadcast -> L1)
    float rcx[RT], rcy[RT], rw[RT], rh[RT];
    float rx0[RT], ry0[RT], rx1[RT], ry1[RT], rar[RT];
    #pragma unroll
    for (int j = 0; j < RT; ++j) {
        float4 bb = ((const float4*)boxes)[rbase + j];
        rcx[j] = bb.x; rcy[j] = bb.y; rw[j] = bb.z; rh[j] = bb.w;
        rx0[j] = bb.x - 0.5f * bb.z; ry0[j] = bb.y - 0.5f * bb.w;
        rx1[j] = bb.x + 0.5f * bb.z; ry1[j] = bb.y + 0.5f * bb.w;
        rar[j] = (rx1[j] - rx0[j]) * (ry1[j] - ry0[j]);
    }
    __syncthreads();

    #pragma unroll
    for (int k = 0; k < TK; ++k) {
        const int t = t0 + k * 64 + tl;
        float4 txy = t_xyxy[t];
        float4 tcb = ((const float4*)tbox_raw)[t];
        float  tar = t_area[t];
        int    id  = t_id[t];
        #pragma unroll
        for (int j = 0; j < RT; ++j) {
            // L1 cdist in cxcywh space
            float l1 = fabsf(rcx[j] - tcb.x) + fabsf(rcy[j] - tcb.y)
                     + fabsf(rw[j]  - tcb.z) + fabsf(rh[j]  - tcb.w);
            // intersection / union
            float ltx = fmaxf(rx0[j], txy.x), lty = fmaxf(ry0[j], txy.y);
            float rbx = fminf(rx1[j], txy.z), rby = fminf(ry1[j], txy.w);
            float iw = fmaxf(rbx - ltx, 0.0f), ih = fmaxf(rby - lty, 0.0f);
            float inter = iw * ih;
            float uni = rar[j] + tar - inter;
            float iou = inter * __builtin_amdgcn_rcpf(uni);
            // enclosing box
            float ex0 = fminf(rx0[j], txy.x), ey0 = fminf(ry0[j], txy.y);
            float ex1 = fmaxf(rx1[j], txy.z), ey1 = fmaxf(ry1[j], txy.w);
            float ew = fmaxf(ex1 - ex0, 0.0f), eh = fmaxf(ey1 - ey0, 0.0f);
            float ea = ew * eh;
            float giou = iou - (ea - uni) * __builtin_amdgcn_rcpf(ea);
            // C = 5*l1 + 1*(-prob) + 2*(-giou)
            float c = 5.0f * l1 + negp[rg * RT + j][id] - 2.0f * giou;
            out[(long)(rbase + j) * TT + t] = c;
        }
    }
}

// ---------------------------------------------------------------------------
extern "C" void kernel_launch(void* const* d_in, const int* in_sizes, int n_in,
                              void* d_out, int out_size, void* d_ws, size_t ws_size,
                              hipStream_t stream) {
    const float* logits = (const float*)d_in[0];   // [16,900,92] f32
    const float* boxes  = (const float*)d_in[1];   // [16,900,4]  f32
    const int*   tids   = (const int*)  d_in[2];   // [1600] int32
    const float* tbox   = (const float*)d_in[3];   // [1600,4] f32
    float* out = (float*)d_out;

    char* ws = (char*)d_ws;
    float2* stats   = (float2*)(ws + WS_STATS);
    float4* t_xyxy  = (float4*)(ws + WS_XYXY);
    float*  t_area  = (float*) (ws + WS_AREA);
    int*    t_id    = (int*)   (ws + WS_ID);

    k_rowstats<<<BQ / 4, 256, 0, stream>>>(logits, stats);
    k_tgt<<<(TT + 255) / 256, 256, 0, stream>>>(tbox, tids, t_xyxy, t_area, t_id);
    k_cost<<<dim3(BQ / RTILE, TT / (TK * 64)), 256, 0, stream>>>(
        logits, boxes, stats, t_xyxy, t_area, t_id, tbox, out);
}

// Round 2
// 42.475 us; speedup vs baseline: 1.0308x; 1.0308x over previous
//
#include <hip/hip_runtime.h>
#include <math.h>

// Problem constants (from reference setup_inputs)
#define BB 16
#define QQ 900
#define NC 92
#define TT 1600
#define BQ (BB * QQ)   // 14400

// ws layout: float2 rowstats[BQ] = 115200 B
#define WS_STATS  0

// ---------------------------------------------------------------------------
// Kernel A: per-row softmax stats (max, 1/sum_exp). One wave per row of 92.
// ---------------------------------------------------------------------------
__global__ __launch_bounds__(256)
void k_rowstats(const float* __restrict__ logits, float2* __restrict__ stats) {
    const int wave = threadIdx.x >> 6;
    const int lane = threadIdx.x & 63;
    const int row  = blockIdx.x * 4 + wave;    // grid.x = BQ/4 = 3600 exact
    const float* lr = logits + (long)row * NC;
    float v0 = lr[lane];
    float v1 = (lane < NC - 64) ? lr[64 + lane] : -INFINITY;
    float m = fmaxf(v0, v1);
    #pragma unroll
    for (int off = 32; off; off >>= 1) m = fmaxf(m, __shfl_xor(m, off));
    float s = __expf(v0 - m) + ((lane < NC - 64) ? __expf(v1 - m) : 0.0f);
    #pragma unroll
    for (int off = 32; off; off >>= 1) s += __shfl_xor(s, off);
    if (lane == 0) stats[row] = make_float2(m, 1.0f / s);
}

// ---------------------------------------------------------------------------
// Main cost kernel.
//   block = 256 threads = 64 t-lanes x 4 waves; each thread owns RT=8 rows
//   -> 32 rows per block. grid = (BQ/32 = 450, 5); block covers 32 rows x
//   320 targets. LDS: negated softmax probs 32 x 92 fp32 = 11.8 KB.
//   Target data: ONE float4 (cxcywh) + ONE int per lane per k-iter (20 B,
//   L2-resident); xyxy/area derived inline (amortized over 8 outputs).
// ---------------------------------------------------------------------------
#define RT 8        // rows per thread
#define RTILE 32    // rows per block
#define TK 5        // t-iterations of 64 -> 320 targets per block

__global__ __launch_bounds__(256)
void k_cost(const float* __restrict__ logits,
            const float* __restrict__ boxes,       // [BQ,4] cxcywh
            const float2* __restrict__ stats,
            const int* __restrict__ tids,          // [TT] int32
            const float* __restrict__ tbox,        // [TT,4] cxcywh
            float* __restrict__ out) {
    __shared__ float negp[RTILE][NC];              // 11776 B

    const int row0 = blockIdx.x * RTILE;
    const int t0   = blockIdx.y * (TK * 64);

    // stage -prob for the 32 rows of this block
    for (int idx = threadIdx.x; idx < RTILE * NC; idx += 256) {
        int r = idx / NC, c = idx - r * NC;
        int row = row0 + r;
        float2 st = stats[row];
        negp[r][c] = -__expf(logits[row * NC + c] - st.x) * st.y;
    }

    const int tl   = threadIdx.x & 63;
    const int rg   = threadIdx.x >> 6;
    const int rloc = rg * RT;
    const int rbase = row0 + rloc;

    // register-blocked row box data
    float rcx[RT], rcy[RT], rw[RT], rh[RT];
    float rx0[RT], ry0[RT], rx1[RT], ry1[RT], rar[RT];
    #pragma unroll
    for (int j = 0; j < RT; ++j) {
        float4 bb = ((const float4*)boxes)[rbase + j];
        rcx[j] = bb.x; rcy[j] = bb.y; rw[j] = bb.z; rh[j] = bb.w;
        rx0[j] = bb.x - 0.5f * bb.z; ry0[j] = bb.y - 0.5f * bb.w;
        rx1[j] = bb.x + 0.5f * bb.z; ry1[j] = bb.y + 0.5f * bb.w;
        rar[j] = bb.z * bb.w;
    }
    __syncthreads();

    #pragma unroll
    for (int k = 0; k < TK; ++k) {
        const int t = t0 + k * 64 + tl;
        float4 tb = ((const float4*)tbox)[t];      // cx,cy,w,h
        int    id = tids[t];
        float tx0 = tb.x - 0.5f * tb.z, ty0 = tb.y - 0.5f * tb.w;
        float tx1 = tb.x + 0.5f * tb.z, ty1 = tb.y + 0.5f * tb.w;
        float tar = tb.z * tb.w;
        #pragma unroll
        for (int j = 0; j < RT; ++j) {
            // L1 cdist in cxcywh space
            float l1 = fabsf(rcx[j] - tb.x) + fabsf(rcy[j] - tb.y)
                     + fabsf(rw[j]  - tb.z) + fabsf(rh[j]  - tb.w);
            // intersection / union
            float ix0 = fmaxf(rx0[j], tx0), iy0 = fmaxf(ry0[j], ty0);
            float ix1 = fminf(rx1[j], tx1), iy1 = fminf(ry1[j], ty1);
            float iw = fmaxf(ix1 - ix0, 0.0f), ih = fmaxf(iy1 - iy0, 0.0f);
            float inter = iw * ih;
            float uni = rar[j] + tar - inter;
            // enclosing box (no clamp needed: ex1>=ex0, ey1>=ey0 always)
            float ex0 = fminf(rx0[j], tx0), ey0 = fminf(ry0[j], ty0);
            float ex1 = fmaxf(rx1[j], tx1), ey1 = fmaxf(ry1[j], ty1);
            float ea = (ex1 - ex0) * (ey1 - ey0);
            // giou = inter/uni - 1 + uni/ea  -> single rcp:
            // num = ea*(inter-uni) + uni^2 ; giou = num / (uni*ea)
            float num = fmaf(ea, inter - uni, uni * uni);
            float rden = __builtin_amdgcn_rcpf(uni * ea);
            // C = 5*l1 + (-prob) - 2*giou
            float c = fmaf(5.0f, l1, negp[rloc + j][id]) - 2.0f * (num * rden);
            out[(unsigned)(rbase + j) * TT + t] = c;
        }
    }
}

// ---------------------------------------------------------------------------
extern "C" void kernel_launch(void* const* d_in, const int* in_sizes, int n_in,
                              void* d_out, int out_size, void* d_ws, size_t ws_size,
                              hipStream_t stream) {
    const float* logits = (const float*)d_in[0];   // [16,900,92] f32
    const float* boxes  = (const float*)d_in[1];   // [16,900,4]  f32
    const int*   tids   = (const int*)  d_in[2];   // [1600] int32
    const float* tbox   = (const float*)d_in[3];   // [1600,4] f32
    float* out = (float*)d_out;

    float2* stats = (float2*)((char*)d_ws + WS_STATS);

    k_rowstats<<<BQ / 4, 256, 0, stream>>>(logits, stats);
    k_cost<<<dim3(BQ / RTILE, TT / (TK * 64)), 256, 0, stream>>>(
        logits, boxes, stats, tids, tbox, out);
}

// Round 3
// 32.358 us; speedup vs baseline: 1.3531x; 1.3126x over previous
//
#include <hip/hip_runtime.h>
#include <math.h>

// Problem constants (from reference setup_inputs)
#define BB 16
#define QQ 900
#define NC 92
#define NCP 96          // padded LDS row (exact 12 staging iters, zero pad)
#define TT 1600
#define BQ (BB * QQ)    // 14400

// ---------------------------------------------------------------------------
// Fully fused cost kernel.
//   grid = (BQ/32 = 450, TT/320 = 5), block = 256 = 4 waves.
//   Wave rg owns 8 rows (RT=8); its 64 lanes sweep targets.
//   LDS: unnormalized exp(logits) for the 32 rows, [32][96] f32 = 12 KB.
//   Softmax denominators computed in-wave (no helper kernel, no ws):
//     8 lanes per row sum 12 padded columns -> 3x shfl_xor -> rcp.
//   GIoU enclosing box via min+max identity: enc_w = rw + tw - iwu.
// ---------------------------------------------------------------------------
#define RT 8        // rows per thread (= rows per wave)
#define RTILE 32    // rows per block
#define TK 5        // t-iterations of 64 -> 320 targets per block

__global__ __launch_bounds__(256)
void k_cost(const float* __restrict__ logits,
            const float* __restrict__ boxes,       // [BQ,4] cxcywh
            const int* __restrict__ tids,          // [TT] int32
            const float* __restrict__ tbox,        // [TT,4] cxcywh
            float* __restrict__ out) {
    __shared__ float pexp[RTILE][NCP];             // 12288 B

    const int row0 = blockIdx.x * RTILE;
    const int t0   = blockIdx.y * (TK * 64);

    // ---- stage unnormalized exp(logit); pad cols 92..95 with 0 ----
    #pragma unroll
    for (int it = 0; it < (RTILE * NCP) / 256; ++it) {    // 12 iters
        int idx = it * 256 + threadIdx.x;
        int r = idx / NCP, c = idx - r * NCP;
        float v = 0.0f;
        if (c < NC) v = __expf(logits[(row0 + r) * NC + c]);
        pexp[r][c] = v;
    }

    const int tl   = threadIdx.x & 63;
    const int rg   = threadIdx.x >> 6;
    const int rloc = rg * RT;
    const int rbase = row0 + rloc;

    // ---- register-blocked row box data ----
    float rcx[RT], rcy[RT], rw[RT], rh[RT];
    float rx0[RT], ry0[RT], rx1[RT], ry1[RT], rar[RT];
    #pragma unroll
    for (int j = 0; j < RT; ++j) {
        float4 bb = ((const float4*)boxes)[rbase + j];
        rcx[j] = bb.x; rcy[j] = bb.y; rw[j] = bb.z; rh[j] = bb.w;
        rx0[j] = bb.x - 0.5f * bb.z; ry0[j] = bb.y - 0.5f * bb.w;
        rx1[j] = bb.x + 0.5f * bb.z; ry1[j] = bb.y + 0.5f * bb.w;
        rar[j] = bb.z * bb.w;
    }
    __syncthreads();

    // ---- in-wave softmax denominators for this wave's 8 rows ----
    // lane l: row rloc + (l>>3), columns (l&7)*12 .. +11 (pad cols are 0)
    {
        const int lr = tl >> 3;          // 0..7 local row
        const int ls = tl & 7;           // 8 lanes per row
        float s = 0.0f;
        #pragma unroll
        for (int i = 0; i < 12; ++i) s += pexp[rloc + lr][ls * 12 + i];
        s += __shfl_xor(s, 1);
        s += __shfl_xor(s, 2);
        s += __shfl_xor(s, 4);
        // broadcast: row rloc+j's sum lives in lanes j*8..j*8+7
        #pragma unroll
        for (int j = 0; j < RT; ++j)
            rar[j] = rar[j];             // keep arrays alive (no-op)
        float rinv[RT];
        #pragma unroll
        for (int j = 0; j < RT; ++j)
            rinv[j] = __builtin_amdgcn_rcpf(__shfl(s, j * 8));

        // ---- main loop: 5 x 64 targets ----
        #pragma unroll
        for (int k = 0; k < TK; ++k) {
            const int t = t0 + k * 64 + tl;
            float4 tb = ((const float4*)tbox)[t];      // cx,cy,w,h
            int    id = tids[t];
            float tx0 = tb.x - 0.5f * tb.z, ty0 = tb.y - 0.5f * tb.w;
            float tx1 = tb.x + 0.5f * tb.z, ty1 = tb.y + 0.5f * tb.w;
            float tar = tb.z * tb.w;
            #pragma unroll
            for (int j = 0; j < RT; ++j) {
                // L1 cdist in cxcywh space
                float l1 = fabsf(rcx[j] - tb.x) + fabsf(rcy[j] - tb.y)
                         + fabsf(rw[j]  - tb.z) + fabsf(rh[j]  - tb.w);
                // unclamped intersection extents
                float iwu = fminf(rx1[j], tx1) - fmaxf(rx0[j], tx0);
                float ihu = fminf(ry1[j], ty1) - fmaxf(ry0[j], ty0);
                float inter = fmaxf(iwu, 0.0f) * fmaxf(ihu, 0.0f);
                float uni = rar[j] + tar - inter;
                // enclosing box via min+max identity (always non-negative)
                float ew = (rw[j] + tb.z) - iwu;
                float eh = (rh[j] + tb.w) - ihu;
                float ea = ew * eh;
                // giou = (ea*(inter-uni) + uni^2) / (uni*ea), single rcp
                float num = fmaf(ea, inter - uni, uni * uni);
                float rden = __builtin_amdgcn_rcpf(uni * ea);
                // C = 5*l1 - prob - 2*giou
                float p = pexp[rloc + j][id];
                float c = fmaf(-p, rinv[j], 5.0f * l1);
                c = fmaf(-2.0f * num, rden, c);
                __builtin_nontemporal_store(c, &out[(rbase + j) * TT + t]);
            }
        }
    }
}

// ---------------------------------------------------------------------------
extern "C" void kernel_launch(void* const* d_in, const int* in_sizes, int n_in,
                              void* d_out, int out_size, void* d_ws, size_t ws_size,
                              hipStream_t stream) {
    const float* logits = (const float*)d_in[0];   // [16,900,92] f32
    const float* boxes  = (const float*)d_in[1];   // [16,900,4]  f32
    const int*   tids   = (const int*)  d_in[2];   // [1600] int32
    const float* tbox   = (const float*)d_in[3];   // [1600,4] f32
    float* out = (float*)d_out;

    k_cost<<<dim3(BQ / RTILE, TT / (TK * 64)), 256, 0, stream>>>(
        logits, boxes, tids, tbox, out);
}

// Round 4
// 29.509 us; speedup vs baseline: 1.4837x; 1.0965x over previous
//
#include <hip/hip_runtime.h>
#include <math.h>

// Problem constants (from reference setup_inputs)
#define BB 16
#define QQ 900
#define NC 92
#define NCP 96          // padded LDS row
#define TT 1600
#define BQ (BB * QQ)    // 14400

// ---------------------------------------------------------------------------
// Fully fused cost kernel, occupancy-optimized.
//   grid = (BQ/16 = 900, TT/320 = 5), block = 256 = 4 waves.
//   Wave rg owns RT=4 rows; its 64 lanes sweep 5x64 targets.
//   LDS: unnormalized exp(logits) [16][96] f32 = 6 KB.
//   Softmax denominators in-wave: 16 lanes/row x 6 cols + 4x shfl_xor.
//   GIoU enclosing box via min+max identity: enc_w = rw + tw - iwu.
//   RT=4 keeps VGPR ~70 -> ~7 waves/SIMD resident (latency hiding).
// ---------------------------------------------------------------------------
#define RT 4        // rows per thread (= rows per wave)
#define RTILE 16    // rows per block
#define TK 5        // t-iterations of 64 -> 320 targets per block

__global__ __launch_bounds__(256)
void k_cost(const float* __restrict__ logits,
            const float* __restrict__ boxes,       // [BQ,4] cxcywh
            const int* __restrict__ tids,          // [TT] int32
            const float* __restrict__ tbox,        // [TT,4] cxcywh
            float* __restrict__ out) {
    __shared__ float pexp[RTILE][NCP];             // 6144 B

    const int row0 = blockIdx.x * RTILE;
    const int t0   = blockIdx.y * (TK * 64);

    // ---- stage unnormalized exp(logit) via float2; pad cols 92..95 = 0 ----
    #pragma unroll
    for (int it = 0; it < 3; ++it) {               // 3 x 512 floats = 16*96
        int idx = it * 512 + threadIdx.x * 2;
        int r = idx / NCP, c = idx - r * NCP;      // c even
        float2 v = make_float2(0.0f, 0.0f);
        if (c < NC) {
            float2 lv = *(const float2*)&logits[(row0 + r) * NC + c];
            v.x = __expf(lv.x);
            v.y = __expf(lv.y);
        }
        *(float2*)&pexp[r][c] = v;
    }

    const int tl   = threadIdx.x & 63;
    const int rg   = threadIdx.x >> 6;
    const int rloc = rg * RT;
    const int rbase = row0 + rloc;

    // ---- register-blocked row box data ----
    float rcx[RT], rcy[RT], rw[RT], rh[RT];
    float rx0[RT], ry0[RT], rx1[RT], ry1[RT], rar[RT];
    #pragma unroll
    for (int j = 0; j < RT; ++j) {
        float4 bb = ((const float4*)boxes)[rbase + j];
        rcx[j] = bb.x; rcy[j] = bb.y; rw[j] = bb.z; rh[j] = bb.w;
        rx0[j] = bb.x - 0.5f * bb.z; ry0[j] = bb.y - 0.5f * bb.w;
        rx1[j] = bb.x + 0.5f * bb.z; ry1[j] = bb.y + 0.5f * bb.w;
        rar[j] = bb.z * bb.w;
    }
    __syncthreads();

    // ---- in-wave softmax denominators for this wave's 4 rows ----
    // lane l: row rloc + (l>>4), cols (l&15)*6 .. +5  (pad cols are 0)
    float rinv[RT];
    {
        const int lr = tl >> 4;
        const int ls = tl & 15;
        float s = 0.0f;
        #pragma unroll
        for (int i = 0; i < 6; ++i) s += pexp[rloc + lr][ls * 6 + i];
        s += __shfl_xor(s, 1);
        s += __shfl_xor(s, 2);
        s += __shfl_xor(s, 4);
        s += __shfl_xor(s, 8);
        #pragma unroll
        for (int j = 0; j < RT; ++j)
            rinv[j] = __builtin_amdgcn_rcpf(__shfl(s, j * 16));
    }

    // ---- main loop: 5 x 64 targets ----
    #pragma unroll
    for (int k = 0; k < TK; ++k) {
        const int t = t0 + k * 64 + tl;
        float4 tb = ((const float4*)tbox)[t];      // cx,cy,w,h
        int    id = tids[t];
        float tx0 = tb.x - 0.5f * tb.z, ty0 = tb.y - 0.5f * tb.w;
        float tx1 = tb.x + 0.5f * tb.z, ty1 = tb.y + 0.5f * tb.w;
        float tar = tb.z * tb.w;
        #pragma unroll
        for (int j = 0; j < RT; ++j) {
            // L1 cdist in cxcywh space
            float l1 = fabsf(rcx[j] - tb.x) + fabsf(rcy[j] - tb.y)
                     + fabsf(rw[j]  - tb.z) + fabsf(rh[j]  - tb.w);
            // unclamped intersection extents
            float iwu = fminf(rx1[j], tx1) - fmaxf(rx0[j], tx0);
            float ihu = fminf(ry1[j], ty1) - fmaxf(ry0[j], ty0);
            float inter = fmaxf(iwu, 0.0f) * fmaxf(ihu, 0.0f);
            float uni = rar[j] + tar - inter;
            // enclosing box via min+max identity (always non-negative)
            float ew = (rw[j] + tb.z) - iwu;
            float eh = (rh[j] + tb.w) - ihu;
            float ea = ew * eh;
            // giou = (ea*(inter-uni) + uni^2) / (uni*ea), single rcp
            float num = fmaf(ea, inter - uni, uni * uni);
            float rden = __builtin_amdgcn_rcpf(uni * ea);
            // C = 5*l1 - prob - 2*giou
            float p = pexp[rloc + j][id];
            float c = fmaf(-p, rinv[j], 5.0f * l1);
            c = fmaf(-2.0f * num, rden, c);
            __builtin_nontemporal_store(c, &out[(rbase + j) * TT + t]);
        }
    }
}

// ---------------------------------------------------------------------------
extern "C" void kernel_launch(void* const* d_in, const int* in_sizes, int n_in,
                              void* d_out, int out_size, void* d_ws, size_t ws_size,
                              hipStream_t stream) {
    const float* logits = (const float*)d_in[0];   // [16,900,92] f32
    const float* boxes  = (const float*)d_in[1];   // [16,900,4]  f32
    const int*   tids   = (const int*)  d_in[2];   // [1600] int32
    const float* tbox   = (const float*)d_in[3];   // [1600,4] f32
    float* out = (float*)d_out;

    k_cost<<<dim3(BQ / RTILE, TT / (TK * 64)), 256, 0, stream>>>(
        logits, boxes, tids, tbox, out);
}